// Round 14
// baseline (21.302 us; speedup 1.0000x reference)
//
#include <hip/hip_runtime.h>
#include <hip/hip_bf16.h>

#define N_ATOMS 51200

// Output layout (flat floats, reference return order):
//   energy[512]@0, forces[153600]@512, stress[4608]@154112,
//   energy_uncert[512]@158720 (=0.6), force_uncert[153600]@159232 (computed),
//   stress_uncert[4608]@312832 (=0.1/16)
#define OUT_FUNC 159232

typedef __attribute__((ext_vector_type(4))) float f32x4;
typedef __attribute__((ext_vector_type(4))) unsigned u32x4;
typedef __attribute__((ext_vector_type(8))) short s16x8;

constexpr int BLK = 256;

__device__ __forceinline__ unsigned pack2(float lo, float hi) {
    return __builtin_amdgcn_perm(__float_as_uint(hi), __float_as_uint(lo), 0x07060302);
}
__device__ __forceinline__ s16x8 pack8(f32x4 lo, f32x4 hi) {
    union { u32x4 u; s16x8 s; } c;
    c.u.x = pack2(lo.x, lo.y); c.u.y = pack2(lo.z, lo.w);
    c.u.z = pack2(hi.x, hi.y); c.u.w = pack2(hi.z, hi.w);
    return c.s;
}
__device__ __forceinline__ short bftrunc(float x) {
    return (short)(__float_as_uint(x) >> 16);
}
__device__ __forceinline__ float silu_(float v) { return v / (1.0f + __expf(-v)); }

__global__ __launch_bounds__(BLK, 4) void funcert_kernel(
    const float* __restrict__ nf,
    const float* __restrict__ energy,
    const float* __restrict__ forces,
    const float* __restrict__ stress,
    const float* __restrict__ W1f, const float* __restrict__ b1f,
    const float* __restrict__ W2f, const float* __restrict__ b2f,
    const float* __restrict__ W3f, const float* __restrict__ b3f,
    float* __restrict__ out)
{
    const int t   = threadIdx.x;
    const int gid = blockIdx.x * BLK + t;

    // X staged as f32 via global_load_lds DMA; swizzle applied on SOURCE addr
    __shared__ float Xq[2][64 * 64];   // 2 x 16 KB quarter tiles
    __shared__ short H1s[64 * 64];     // 8 KB

    const int lane  = t & 63;
    const int w     = t >> 6;
    const int g     = lane >> 4;
    const int col   = lane & 15;
    const int abase = blockIdx.x * 64;
    const int ch    = w * 16 + col;

    const int rloc = lane >> 4;        // row within a 4-row DMA group
    const int sl   = lane & 15;        // dest 16B slot within the row

    // 4 DMA instructions per wave per quarter; each stages 4 rows x 256B.
    // LDS linear dest; global source pre-swizzled: slot sl holds chunk sl^((r&7)<<1).
    #define GLD_Q(b, qf)                                                     \
        { _Pragma("unroll")                                                  \
          for (int i2 = 0; i2 < 4; ++i2) {                                   \
              const int ii = w * 4 + i2;                                     \
              const int r  = 4 * ii + rloc;                                  \
              const int c  = sl ^ ((r & 7) << 1);                            \
              const float* src = nf + (size_t)(abase + r) * 384 + (qf) + c * 4; \
              __builtin_amdgcn_global_load_lds(                              \
                  (const __attribute__((address_space(1))) void*)src,        \
                  (__attribute__((address_space(3))) void*)(&Xq[b][ii * 256]), \
                  16, 0, 0);                                                 \
          } }

    #define WQ_ISSUE(dst, q)                                                 \
        { _Pragma("unroll")                                                  \
          for (int ks2 = 0; ks2 < 2; ++ks2) {                                \
              const float* p = W1f + ch * 256 + (q) * 64 + ks2 * 32 + g * 8; \
              dst[2 * ks2]     = *(const f32x4*)p;                           \
              dst[2 * ks2 + 1] = *(const f32x4*)(p + 4);                     \
          } }

    // fragment read: floats [ks2*32+g*8, +8) of row -> slots {s0, s0+1}, s0 even
    #define Q_COMPUTE(b, wfv)                                                \
        { _Pragma("unroll")                                                  \
          for (int mt = 0; mt < 4; ++mt) {                                   \
              const int row = mt * 16 + col;                                 \
              const int xr  = (row & 7) << 1;                                \
              _Pragma("unroll")                                              \
              for (int ks2 = 0; ks2 < 2; ++ks2) {                            \
                  const int s0 = ((ks2 << 3) + (g << 1)) ^ xr;               \
                  const float* p = &Xq[b][row * 64 + s0 * 4];                \
                  const f32x4 lo = *(const f32x4*)p;                         \
                  const f32x4 hi = *(const f32x4*)(p + 4);                   \
                  acc[mt] = __builtin_amdgcn_mfma_f32_16x16x32_bf16(         \
                              pack8(lo, hi), wfv[ks2], acc[mt], 0, 0, 0);    \
              } } }

    // ---- copy load first (oldest in queue); store deferred to the end ----
    f32x4 cv = {0.f, 0.f, 0.f, 0.f}; int co = -1;
    if (gid < 40960) {
        co = gid;
        if      (gid < 128)   { cv = ((const f32x4*)energy)[gid]; }
        else if (gid < 38528) { cv = ((const f32x4*)forces)[gid - 128]; }
        else if (gid < 39680) { cv = ((const f32x4*)stress)[gid - 38528]; }
        else if (gid < 39808) { cv = (f32x4){0.6f, 0.6f, 0.6f, 0.6f}; }
        else { cv = (f32x4){0.00625f, 0.00625f, 0.00625f, 0.00625f}; co = gid + 38400; }
    }

    // ---- prologue: W0 (VGPR), then DMA Q0 ----
    f32x4 wv[4];
    WQ_ISSUE(wv, 0);
    const float b1v = b1f[ch];
    GLD_Q(0, 0);                          // Q0 -> buf0 (f4 cols [0,64) floats)

    s16x8 wf[2];
    wf[0] = pack8(wv[0], wv[1]); wf[1] = pack8(wv[2], wv[3]);  // waits W0 only

    f32x4 acc[4];
    #pragma unroll
    for (int mt = 0; mt < 4; ++mt) acc[mt] = (f32x4){0.f, 0.f, 0.f, 0.f};

    __syncthreads();                      // Q0 resident
    WQ_ISSUE(wv, 1);
    GLD_Q(1, 64);                         // Q1 -> buf1
    Q_COMPUTE(0, wf);                     // compute Q0 (ds_read, lgkm only)
    __syncthreads();                      // Q1 resident (drains W1 too)

    wf[0] = pack8(wv[0], wv[1]); wf[1] = pack8(wv[2], wv[3]);  // instant (drained)
    WQ_ISSUE(wv, 2);
    GLD_Q(0, 256);                        // Q2 -> buf0 (concat jump)
    Q_COMPUTE(1, wf);
    __syncthreads();                      // Q2 resident

    wf[0] = pack8(wv[0], wv[1]); wf[1] = pack8(wv[2], wv[3]);
    WQ_ISSUE(wv, 3);
    GLD_Q(1, 320);                        // Q3 -> buf1
    Q_COMPUTE(0, wf);
    __syncthreads();                      // Q3 resident

    wf[0] = pack8(wv[0], wv[1]); wf[1] = pack8(wv[2], wv[3]);
    Q_COMPUTE(1, wf);

    // ---- bias + silu -> h1 (verified layout) ----
    #pragma unroll
    for (int mt = 0; mt < 4; ++mt) {
        #pragma unroll
        for (int r = 0; r < 4; ++r) {
            const int atom = mt * 16 + g * 4 + r;
            H1s[atom * 64 + ch] = bftrunc(silu_(acc[mt][r] + b1v));
        }
    }
    __syncthreads();

    // ---- L2: wave w -> atoms [16w,16w+16), 2 k-steps over 64 ch ----
    s16x8 w2frag[2];
    #pragma unroll
    for (int ks = 0; ks < 2; ++ks) {
        const float* p = W2f + col * 64 + ks * 32 + g * 8;   // B2[k][n] = W2f[n][k]
        w2frag[ks] = pack8(*(const f32x4*)p, *(const f32x4*)(p + 4));
    }
    const int arow = w * 16 + col;
    f32x4 a2 = {0.f, 0.f, 0.f, 0.f};
    #pragma unroll
    for (int ks = 0; ks < 2; ++ks) {
        const s16x8 af = *(const s16x8*)(H1s + arow * 64 + ks * 32 + g * 8);
        a2 = __builtin_amdgcn_mfma_f32_16x16x32_bf16(af, w2frag[ks], a2, 0, 0, 0);
    }

    // ---- h2 + L3 + exp ----
    const float b2v = b2f[col];
    const float w3v = W3f[col];
    float y[4];
    #pragma unroll
    for (int r = 0; r < 4; ++r)
        y[r] = silu_(a2[r] + b2v) * w3v;
    #pragma unroll
    for (int m = 1; m < 16; m <<= 1) {
        #pragma unroll
        for (int r = 0; r < 4; ++r)
            y[r] += __shfl_xor(y[r], m, 64);   // reduce over 16 cols
    }
    const float b3v = b3f[0];
    float fu[4];
    #pragma unroll
    for (int r = 0; r < 4; ++r)
        fu[r] = __expf(y[r] + b3v) * 0.1f;

    if (col < 12) {                            // 4 atoms x 3 comps per 16-lane group
        const int a_ = col / 3, c = col - a_ * 3;
        const float v = (a_ == 0) ? fu[0] : (a_ == 1) ? fu[1] : (a_ == 2) ? fu[2] : fu[3];
        const int atom = w * 16 + g * 4 + a_;
        out[OUT_FUNC + 3 * (abase + atom) + c] = v;
    }

    // ---- deferred passthrough store (cv long retired; zero wait) ----
    if (co >= 0) ((f32x4*)out)[co] = cv;
}

extern "C" void kernel_launch(void* const* d_in, const int* in_sizes, int n_in,
                              void* d_out, int out_size, void* d_ws, size_t ws_size,
                              hipStream_t stream) {
    const float* nf     = (const float*)d_in[0];
    const float* energy = (const float*)d_in[1];
    const float* forces = (const float*)d_in[2];
    const float* stress = (const float*)d_in[3];
    const float* W1f    = (const float*)d_in[10];
    const float* b1f    = (const float*)d_in[11];
    const float* W2f    = (const float*)d_in[12];
    const float* b2f    = (const float*)d_in[13];
    const float* W3f    = (const float*)d_in[14];
    const float* b3f    = (const float*)d_in[15];
    float* out = (float*)d_out;

    dim3 grid(N_ATOMS / 64);   // 800 blocks
    funcert_kernel<<<grid, BLK, 0, stream>>>(nf, energy, forces, stress,
                                             W1f, b1f, W2f, b2f, W3f, b3f, out);
}

// Round 15
// 21.043 us; speedup vs baseline: 1.0123x; 1.0123x over previous
//
#include <hip/hip_runtime.h>
#include <hip/hip_bf16.h>

#define N_ATOMS 51200

// Output layout (flat floats, reference return order):
//   energy[512]@0, forces[153600]@512, stress[4608]@154112,
//   energy_uncert[512]@158720 (=0.6), force_uncert[153600]@159232 (computed),
//   stress_uncert[4608]@312832 (=0.1/16)
#define OUT_FUNC 159232

typedef __attribute__((ext_vector_type(4))) float f32x4;
typedef __attribute__((ext_vector_type(4))) unsigned u32x4;
typedef __attribute__((ext_vector_type(8))) short s16x8;

constexpr int BLK = 256;

__device__ __forceinline__ unsigned pack2(float lo, float hi) {
    return __builtin_amdgcn_perm(__float_as_uint(hi), __float_as_uint(lo), 0x07060302);
}
__device__ __forceinline__ s16x8 pack8(f32x4 lo, f32x4 hi) {
    union { u32x4 u; s16x8 s; } c;
    c.u.x = pack2(lo.x, lo.y); c.u.y = pack2(lo.z, lo.w);
    c.u.z = pack2(hi.x, hi.y); c.u.w = pack2(hi.z, hi.w);
    return c.s;
}
__device__ __forceinline__ short bftrunc(float x) {
    return (short)(__float_as_uint(x) >> 16);
}
__device__ __forceinline__ float silu_(float v) { return v / (1.0f + __expf(-v)); }

// Raw barrier discipline (T3/T4): counted vmcnt, NEVER vmcnt(0) mid-loop.
#define VMCNT8()  asm volatile("s_waitcnt vmcnt(8)" ::: "memory")
#define VMCNT0()  asm volatile("s_waitcnt vmcnt(0)" ::: "memory")
#define LGKM0()   asm volatile("s_waitcnt lgkmcnt(0)" ::: "memory")
#define RAWBAR()  asm volatile("s_barrier" ::: "memory")

__global__ __launch_bounds__(BLK, 4) void funcert_kernel(
    const float* __restrict__ nf,
    const float* __restrict__ energy,
    const float* __restrict__ forces,
    const float* __restrict__ stress,
    const float* __restrict__ W1f, const float* __restrict__ b1f,
    const float* __restrict__ W2f, const float* __restrict__ b2f,
    const float* __restrict__ W3f, const float* __restrict__ b3f,
    float* __restrict__ out)
{
    const int t   = threadIdx.x;
    const int gid = blockIdx.x * BLK + t;

    __shared__ float Xq[2][64 * 64];   // 2 x 16 KB f32 quarter tiles (DMA dest)
    __shared__ short H1s[64 * 64];     // 8 KB

    const int lane  = t & 63;
    const int w     = t >> 6;
    const int g     = lane >> 4;
    const int col   = lane & 15;
    const int abase = blockIdx.x * 64;
    const int ch    = w * 16 + col;

    const int rloc = lane >> 4;        // row within a 4-row DMA group
    const int sl   = lane & 15;        // dest 16B slot within the row

    // 4 DMA instrs/wave/quarter; LDS linear dest, swizzle on SOURCE (verified R14)
    #define GLD_Q(b, qf)                                                     \
        { _Pragma("unroll")                                                  \
          for (int i2 = 0; i2 < 4; ++i2) {                                   \
              const int ii = w * 4 + i2;                                     \
              const int r  = 4 * ii + rloc;                                  \
              const int c  = sl ^ ((r & 7) << 1);                            \
              const float* src = nf + (size_t)(abase + r) * 384 + (qf) + c * 4; \
              __builtin_amdgcn_global_load_lds(                              \
                  (const __attribute__((address_space(1))) void*)src,        \
                  (__attribute__((address_space(3))) void*)(&Xq[b][ii * 256]), \
                  16, 0, 0);                                                 \
          } }

    #define WQ_ISSUE(dst, q)                                                 \
        { _Pragma("unroll")                                                  \
          for (int ks2 = 0; ks2 < 2; ++ks2) {                                \
              const float* p = W1f + ch * 256 + (q) * 64 + ks2 * 32 + g * 8; \
              dst[2 * ks2]     = *(const f32x4*)p;                           \
              dst[2 * ks2 + 1] = *(const f32x4*)(p + 4);                     \
          } }

    #define Q_COMPUTE(b, wfv)                                                \
        { _Pragma("unroll")                                                  \
          for (int mt = 0; mt < 4; ++mt) {                                   \
              const int row = mt * 16 + col;                                 \
              const int xr  = (row & 7) << 1;                                \
              _Pragma("unroll")                                              \
              for (int ks2 = 0; ks2 < 2; ++ks2) {                            \
                  const int s0 = ((ks2 << 3) + (g << 1)) ^ xr;               \
                  const float* p = &Xq[b][row * 64 + s0 * 4];                \
                  const f32x4 lo = *(const f32x4*)p;                         \
                  const f32x4 hi = *(const f32x4*)(p + 4);                   \
                  acc[mt] = __builtin_amdgcn_mfma_f32_16x16x32_bf16(         \
                              pack8(lo, hi), wfv[ks2], acc[mt], 0, 0, 0);    \
              } } }

    // ---- copy load first (oldest; retires early, never blocks counted waits) ----
    f32x4 cv = {0.f, 0.f, 0.f, 0.f}; int co = -1;
    if (gid < 40960) {
        co = gid;
        if      (gid < 128)   { cv = ((const f32x4*)energy)[gid]; }
        else if (gid < 38528) { cv = ((const f32x4*)forces)[gid - 128]; }
        else if (gid < 39680) { cv = ((const f32x4*)stress)[gid - 38528]; }
        else if (gid < 39808) { cv = (f32x4){0.6f, 0.6f, 0.6f, 0.6f}; }
        else { cv = (f32x4){0.00625f, 0.00625f, 0.00625f, 0.00625f}; co = gid + 38400; }
    }

    // ---- prologue: 2-deep — W0, X0, W1, X1 all in flight ----
    f32x4 wva[4], wvb[4];
    WQ_ISSUE(wva, 0);                      // W0
    GLD_Q(0, 0);                           // X0 -> buf0
    WQ_ISSUE(wvb, 1);                      // W1
    GLD_Q(1, 64);                          // X1 -> buf1
    const float b1v = b1f[ch];

    f32x4 acc[4];
    #pragma unroll
    for (int mt = 0; mt < 4; ++mt) acc[mt] = (f32x4){0.f, 0.f, 0.f, 0.f};
    s16x8 wf[2];

    // ---- phase 0: X0 resident (leave W1+X1=8 in flight) ----
    VMCNT8(); RAWBAR();
    wf[0] = pack8(wva[0], wva[1]); wf[1] = pack8(wva[2], wva[3]);
    Q_COMPUTE(0, wf);
    LGKM0(); RAWBAR();                     // all waves done reading buf0
    WQ_ISSUE(wva, 2);                      // W2
    GLD_Q(0, 256);                         // X2 -> buf0 (concat jump)

    // ---- phase 1: X1 resident (leave W2+X2=8) ----
    VMCNT8(); RAWBAR();
    wf[0] = pack8(wvb[0], wvb[1]); wf[1] = pack8(wvb[2], wvb[3]);
    Q_COMPUTE(1, wf);
    LGKM0(); RAWBAR();                     // all waves done reading buf1
    WQ_ISSUE(wvb, 3);                      // W3
    GLD_Q(1, 320);                         // X3 -> buf1

    // ---- phase 2: X2 resident (leave W3+X3=8) ----
    VMCNT8(); RAWBAR();
    wf[0] = pack8(wva[0], wva[1]); wf[1] = pack8(wva[2], wva[3]);
    Q_COMPUTE(0, wf);

    // ---- phase 3: X3 resident (final drain is free here) ----
    VMCNT0(); RAWBAR();
    wf[0] = pack8(wvb[0], wvb[1]); wf[1] = pack8(wvb[2], wvb[3]);
    Q_COMPUTE(1, wf);

    // ---- bias + silu -> h1 (verified layout) ----
    #pragma unroll
    for (int mt = 0; mt < 4; ++mt) {
        #pragma unroll
        for (int r = 0; r < 4; ++r) {
            const int atom = mt * 16 + g * 4 + r;
            H1s[atom * 64 + ch] = bftrunc(silu_(acc[mt][r] + b1v));
        }
    }
    __syncthreads();

    // ---- L2: wave w -> atoms [16w,16w+16), 2 k-steps over 64 ch ----
    s16x8 w2frag[2];
    #pragma unroll
    for (int ks = 0; ks < 2; ++ks) {
        const float* p = W2f + col * 64 + ks * 32 + g * 8;   // B2[k][n] = W2f[n][k]
        w2frag[ks] = pack8(*(const f32x4*)p, *(const f32x4*)(p + 4));
    }
    const int arow = w * 16 + col;
    f32x4 a2 = {0.f, 0.f, 0.f, 0.f};
    #pragma unroll
    for (int ks = 0; ks < 2; ++ks) {
        const s16x8 af = *(const s16x8*)(H1s + arow * 64 + ks * 32 + g * 8);
        a2 = __builtin_amdgcn_mfma_f32_16x16x32_bf16(af, w2frag[ks], a2, 0, 0, 0);
    }

    // ---- h2 + L3 + exp ----
    const float b2v = b2f[col];
    const float w3v = W3f[col];
    float y[4];
    #pragma unroll
    for (int r = 0; r < 4; ++r)
        y[r] = silu_(a2[r] + b2v) * w3v;
    #pragma unroll
    for (int m = 1; m < 16; m <<= 1) {
        #pragma unroll
        for (int r = 0; r < 4; ++r)
            y[r] += __shfl_xor(y[r], m, 64);   // reduce over 16 cols
    }
    const float b3v = b3f[0];
    float fu[4];
    #pragma unroll
    for (int r = 0; r < 4; ++r)
        fu[r] = __expf(y[r] + b3v) * 0.1f;

    if (col < 12) {                            // 4 atoms x 3 comps per 16-lane group
        const int a_ = col / 3, c = col - a_ * 3;
        const float v = (a_ == 0) ? fu[0] : (a_ == 1) ? fu[1] : (a_ == 2) ? fu[2] : fu[3];
        const int atom = w * 16 + g * 4 + a_;
        out[OUT_FUNC + 3 * (abase + atom) + c] = v;
    }

    // ---- deferred passthrough store (cv long retired; zero wait) ----
    if (co >= 0) ((f32x4*)out)[co] = cv;
}

extern "C" void kernel_launch(void* const* d_in, const int* in_sizes, int n_in,
                              void* d_out, int out_size, void* d_ws, size_t ws_size,
                              hipStream_t stream) {
    const float* nf     = (const float*)d_in[0];
    const float* energy = (const float*)d_in[1];
    const float* forces = (const float*)d_in[2];
    const float* stress = (const float*)d_in[3];
    const float* W1f    = (const float*)d_in[10];
    const float* b1f    = (const float*)d_in[11];
    const float* W2f    = (const float*)d_in[12];
    const float* b2f    = (const float*)d_in[13];
    const float* W3f    = (const float*)d_in[14];
    const float* b3f    = (const float*)d_in[15];
    float* out = (float*)d_out;

    dim3 grid(N_ATOMS / 64);   // 800 blocks
    funcert_kernel<<<grid, BLK, 0, stream>>>(nf, energy, forces, stress,
                                             W1f, b1f, W2f, b2f, W3f, b3f, out);
}